// Round 9
// baseline (180.552 us; speedup 1.0000x reference)
//
#include <hip/hip_runtime.h>
#include <hip/hip_bf16.h>

#define T_TOK 8192
#define DDIM 1024
#define HDIM 1024
#define NEXP 8
#define KTOP 2
#define NROWS (T_TOK * KTOP)

typedef __attribute__((ext_vector_type(8))) short bf16x8;
typedef __attribute__((ext_vector_type(4))) float f32x4;

__device__ __forceinline__ unsigned short f2bf(float f) {
    unsigned u = __builtin_bit_cast(unsigned, f);
    u += 0x7fffu + ((u >> 16) & 1u);   // RNE
    return (unsigned short)(u >> 16);
}
__device__ __forceinline__ float bf2f(unsigned short h) {
    return __builtin_bit_cast(float, (unsigned)h << 16);
}

// async global->LDS, 16B per lane; LDS dest wave-uniform base + lane*16.
__device__ __forceinline__ void gll16(const unsigned short* g, const unsigned short* l) {
    __builtin_amdgcn_global_load_lds(
        (const __attribute__((address_space(1))) unsigned int*)g,
        (__attribute__((address_space(3))) unsigned int*)l, 16, 0, 0);
}

// ---------------- prep kernels ----------------

__global__ __launch_bounds__(256) void cvt_bf16_k(const float* __restrict__ in,
                                                  unsigned short* __restrict__ out, int n4) {
    int i = blockIdx.x * 256 + threadIdx.x;
    if (i >= n4) return;
    float4 v = ((const float4*)in)[i];
    ushort4 o;
    o.x = f2bf(v.x); o.y = f2bf(v.y); o.z = f2bf(v.z); o.w = f2bf(v.w);
    ((ushort4*)out)[i] = o;
}

// in: [nmat][R][C] f32  ->  out: [nmat][C][R] bf16
__global__ __launch_bounds__(256) void transpose_cast_k(const float* __restrict__ in,
                                                        unsigned short* __restrict__ out,
                                                        int R, int C) {
    __shared__ unsigned short tile[32][33];
    int m = blockIdx.z;
    const float* src = in + (size_t)m * R * C;
    unsigned short* dst = out + (size_t)m * R * C;
    int c0 = blockIdx.x * 32, r0 = blockIdx.y * 32;
    int tx = threadIdx.x & 31, ty = threadIdx.x >> 5;
#pragma unroll
    for (int i = 0; i < 32; i += 8)
        tile[ty + i][tx] = f2bf(src[(size_t)(r0 + ty + i) * C + c0 + tx]);
    __syncthreads();
#pragma unroll
    for (int i = 0; i < 32; i += 8)
        dst[(size_t)(c0 + ty + i) * R + r0 + tx] = tile[tx][ty + i];
}

// ------------- 256x256 GEMM, BK=64, 2-dbuf, stepped-lgkm fine interleave --------
// C = act(A @ Bt^T + bias). 512 thr = 8 waves (2Mx4N), per-wave 128x64 out.
// 16 K-tiles of 64. Per tile: STAGE(t+1) (8 gll16, other dbuf) -> issue 12
// ds_read (B-s0 x4, A-s0 x8) -> lgkm(4)+16MFMA -> issue 12 s1 reads ->
// lgkm(12)+16MFMA -> lgkm(4)+16MFMA -> lgkm(0)+16MFMA -> vmcnt(0)+barrier.
// Stepped lgkm lets the LDS pipe run UNDER the MFMA pipe (m196's fine
// interleave); vmcnt(0) at the boundary is cheap: those loads were issued a
// full tile (~2400cyc) earlier. WAR: STAGE(t+1) -> buf (t+1)&1 while reading
// buf t&1; RAW: boundary vmcnt(0)+barrier publishes tile t+1.
// Swizzle (BK=64: row=128B line): logical chunk c (16B) of row r stored at
// phys chunk c^(r&7); staging writes linear (gll16) from inverse-swizzled
// global source; reads XOR the same way (rule 21c) -> ~2-way max conflicts.
// T1: XCD-chunked map (XCD x owns expert x's rows).
// MODE 0: Out=acc+bias (row layout). MODE 1: gate -> write per-thread blob
// (vectorized). MODE 2: up -> read blob, Out=silu(g)*(acc+bias) (row layout).

constexpr int BM2 = 256, BN2 = 256, BK2 = 64;
constexpr int NT2 = DDIM / BK2;   // 16 K-tiles
// LDS ushort map: A buf b at b*16384 (32KB); B buf b at 32768 + b*16384.

template <int MODE>
__global__ __launch_bounds__(512) void gemm256_sl_k(
    const unsigned short* __restrict__ A, const int* __restrict__ rowidx, int lda,
    const unsigned short* __restrict__ Bt, const float* __restrict__ biasE,
    const unsigned short* __restrict__ Gblob, unsigned short* __restrict__ Out,
    const int* __restrict__ offsets, int N, int K) {
    __shared__ __attribute__((aligned(16))) unsigned short lds[65536];  // 128 KiB

    // XCD-chunked map: 256 blocks, 8 XCDs, 32 each; brow-major within chunk.
    const int nbn = N / BN2;                          // 4
    int l = (blockIdx.x & 7) * 32 + (blockIdx.x >> 3);
    int brow = l / nbn, bcol = l % nbn;
    int row0 = brow * BM2, col0 = bcol * BN2;
    int e = 0;
    while (offsets[e + 1] <= row0) ++e;

    const unsigned short* Bte = Bt + (size_t)e * N * K;
    const float* bias = biasE + (size_t)e * N;

    int tid = threadIdx.x;
    int lane = tid & 63, wid = tid >> 6;
    int wm = wid >> 2, wn = wid & 3;                  // 2x4 wave grid
    int l15 = lane & 15, l4 = lane >> 4;

    // ---- staging source mapping (inverse swizzle; row = 128B line) ----
    // lane i writes linear slot (row_in_group = i>>3, phys chunk = i&7) which
    // holds logical chunk c = (i&7)^(i>>3) of the same row.
    int srow = lane >> 3;                             // 0..7 within 8-row group
    int scol = ((lane & 7) ^ (lane >> 3)) * 8;        // bf16 elems 0..56
    const unsigned short* asrc[4];
    const unsigned short* bsrc[4];
#pragma unroll
    for (int q = 0; q < 4; ++q) {
        int g = wid * 4 + q;                          // group 0..31 -> rows g*8..+8
        int gr = row0 + g * 8 + srow;
        int ar = rowidx ? rowidx[gr] : gr;
        asrc[q] = A + (size_t)ar * lda + scol;
        bsrc[q] = Bte + (size_t)(col0 + g * 8 + srow) * K + scol;
    }
    unsigned adst[4], bdst[4];
#pragma unroll
    for (int q = 0; q < 4; ++q) {
        adst[q] = (wid * 4 + q) * 512;                // 1KB group per (wave,q)
        bdst[q] = 32768 + (wid * 4 + q) * 512;
    }

#define STAGE(t) { int _b = (t) & 1; int _k = (t) * BK2;              \
        gll16(asrc[0] + _k, lds + _b * 16384 + adst[0]);              \
        gll16(asrc[1] + _k, lds + _b * 16384 + adst[1]);              \
        gll16(asrc[2] + _k, lds + _b * 16384 + adst[2]);              \
        gll16(asrc[3] + _k, lds + _b * 16384 + adst[3]);              \
        gll16(bsrc[0] + _k, lds + _b * 16384 + bdst[0]);              \
        gll16(bsrc[1] + _k, lds + _b * 16384 + bdst[1]);              \
        gll16(bsrc[2] + _k, lds + _b * 16384 + bdst[2]);              \
        gll16(bsrc[3] + _k, lds + _b * 16384 + bdst[3]); }

    // swizzled read byte-offset within a row: chunk (s*4+l4) ^ (row&7); row&7 = l15&7
    int cx = l15 & 7;

    f32x4 acc[8][4] = {};

    // prologue: stage tile 0, drain, publish
    STAGE(0)
    asm volatile("s_waitcnt vmcnt(0)" ::: "memory");
    __builtin_amdgcn_s_barrier();

#pragma unroll 1
    for (int t = 0; t < NT2; ++t) {
        const char* Ab = (const char*)lds + (t & 1) * 32768;
        const char* Bb = (const char*)lds + 65536 + (t & 1) * 32768;
        if (t + 1 < NT2) STAGE(t + 1)

        bf16x8 fb0[4], fb1[4], fa0[8], fa1[8];
        // ---- s0 reads: B x4 then A x8 (12 ds_read_b128) ----
#pragma unroll
        for (int ni = 0; ni < 4; ++ni)
            fb0[ni] = *(const bf16x8*)(Bb + (wn * 64 + ni * 16 + l15) * 128 + ((l4 ^ cx) * 16));
#pragma unroll
        for (int mi = 0; mi < 8; ++mi)
            fa0[mi] = *(const bf16x8*)(Ab + (wm * 128 + mi * 16 + l15) * 128 + ((l4 ^ cx) * 16));
        asm volatile("s_waitcnt lgkmcnt(4)" ::: "memory");   // B0-3 + A0-3 ready
        __builtin_amdgcn_sched_barrier(0);
        __builtin_amdgcn_s_setprio(1);
#pragma unroll
        for (int mi = 0; mi < 4; ++mi)
#pragma unroll
            for (int ni = 0; ni < 4; ++ni)
                acc[mi][ni] = __builtin_amdgcn_mfma_f32_16x16x32_bf16(
                    fa0[mi], fb0[ni], acc[mi][ni], 0, 0, 0);
        __builtin_amdgcn_s_setprio(0);
        // ---- s1 reads issued; then consume remaining s0 ----
#pragma unroll
        for (int ni = 0; ni < 4; ++ni)
            fb1[ni] = *(const bf16x8*)(Bb + (wn * 64 + ni * 16 + l15) * 128 + (((4 + l4) ^ cx) * 16));
#pragma unroll
        for (int mi = 0; mi < 8; ++mi)
            fa1[mi] = *(const bf16x8*)(Ab + (wm * 128 + mi * 16 + l15) * 128 + (((4 + l4) ^ cx) * 16));
        asm volatile("s_waitcnt lgkmcnt(12)" ::: "memory");  // all s0 retired
        __builtin_amdgcn_sched_barrier(0);
        __builtin_amdgcn_s_setprio(1);
#pragma unroll
        for (int mi = 4; mi < 8; ++mi)
#pragma unroll
            for (int ni = 0; ni < 4; ++ni)
                acc[mi][ni] = __builtin_amdgcn_mfma_f32_16x16x32_bf16(
                    fa0[mi], fb0[ni], acc[mi][ni], 0, 0, 0);
        __builtin_amdgcn_s_setprio(0);
        asm volatile("s_waitcnt lgkmcnt(4)" ::: "memory");   // s1 B0-3 + A0-3
        __builtin_amdgcn_sched_barrier(0);
        __builtin_amdgcn_s_setprio(1);
#pragma unroll
        for (int mi = 0; mi < 4; ++mi)
#pragma unroll
            for (int ni = 0; ni < 4; ++ni)
                acc[mi][ni] = __builtin_amdgcn_mfma_f32_16x16x32_bf16(
                    fa1[mi], fb1[ni], acc[mi][ni], 0, 0, 0);
        __builtin_amdgcn_s_setprio(0);
        asm volatile("s_waitcnt lgkmcnt(0)" ::: "memory");
        __builtin_amdgcn_sched_barrier(0);
        __builtin_amdgcn_s_setprio(1);
#pragma unroll
        for (int mi = 4; mi < 8; ++mi)
#pragma unroll
            for (int ni = 0; ni < 4; ++ni)
                acc[mi][ni] = __builtin_amdgcn_mfma_f32_16x16x32_bf16(
                    fa1[mi], fb1[ni], acc[mi][ni], 0, 0, 0);
        __builtin_amdgcn_s_setprio(0);

        // boundary: tile t+1's loads were issued a full tile ago
        if (t + 1 < NT2) {
            asm volatile("s_waitcnt vmcnt(0)" ::: "memory");
            __builtin_amdgcn_s_barrier();
        }
    }
#undef STAGE

    float bv[4];
#pragma unroll
    for (int ni = 0; ni < 4; ++ni)
        bv[ni] = bias[col0 + wn * 64 + ni * 16 + l15];

    if (MODE == 1) {
        // gate: vectorized per-thread blob handoff (same grid/tid in MODE 2)
        ushort4* blob = (ushort4*)Out + ((size_t)blockIdx.x * 512 + tid) * 32;
#pragma unroll
        for (int mi = 0; mi < 8; ++mi)
#pragma unroll
            for (int ni = 0; ni < 4; ++ni) {
                ushort4 o;
                o.x = f2bf(acc[mi][ni][0] + bv[ni]);
                o.y = f2bf(acc[mi][ni][1] + bv[ni]);
                o.z = f2bf(acc[mi][ni][2] + bv[ni]);
                o.w = f2bf(acc[mi][ni][3] + bv[ni]);
                blob[mi * 4 + ni] = o;
            }
    } else {
        const ushort4* blob = (const ushort4*)Gblob + ((size_t)blockIdx.x * 512 + tid) * 32;
#pragma unroll
        for (int mi = 0; mi < 8; ++mi) {
            int orow_b = row0 + wm * 128 + mi * 16 + l4 * 4;
#pragma unroll
            for (int ni = 0; ni < 4; ++ni) {
                int ocol = col0 + wn * 64 + ni * 16 + l15;
                float gq[4];
                if (MODE == 2) {
                    ushort4 g4 = blob[mi * 4 + ni];
                    gq[0] = bf2f(g4.x); gq[1] = bf2f(g4.y);
                    gq[2] = bf2f(g4.z); gq[3] = bf2f(g4.w);
                }
#pragma unroll
                for (int q = 0; q < 4; ++q) {
                    float v = acc[mi][ni][q] + bv[ni];
                    if (MODE == 2) {
                        float g = gq[q];
                        v = (g / (1.0f + __expf(-g))) * v;
                    }
                    Out[(size_t)(orow_b + q) * N + ocol] = f2bf(v);
                }
            }
        }
    }
}

// ---------------- combine ----------------

__global__ __launch_bounds__(256) void combine_k(
    const unsigned short* __restrict__ Y, const int* __restrict__ rev,
    const float* __restrict__ gates, const int* __restrict__ gidx,
    float* __restrict__ out) {
    int t = blockIdx.x;
    int r0 = rev[2 * t], r1 = rev[2 * t + 1];
    float g0 = gates[gidx[2 * t]], g1 = gates[gidx[2 * t + 1]];
    const unsigned short* y0 = Y + (size_t)r0 * DDIM;
    const unsigned short* y1 = Y + (size_t)r1 * DDIM;
    int d = threadIdx.x * 4;
    ushort4 a = *(const ushort4*)(y0 + d);
    ushort4 b = *(const ushort4*)(y1 + d);
    float4 r;
    r.x = g0 * bf2f(a.x) + g1 * bf2f(b.x);
    r.y = g0 * bf2f(a.y) + g1 * bf2f(b.y);
    r.z = g0 * bf2f(a.z) + g1 * bf2f(b.z);
    r.w = g0 * bf2f(a.w) + g1 * bf2f(b.w);
    *(float4*)(out + (size_t)t * DDIM + d) = r;
}

// ---------------- launch ----------------

extern "C" void kernel_launch(void* const* d_in, const int* in_sizes, int n_in,
                              void* d_out, int out_size, void* d_ws, size_t ws_size,
                              hipStream_t stream) {
    const int* offsets = (const int*)d_in[0];
    const float* jagged = (const float*)d_in[1];
    const float* weight = (const float*)d_in[2];
    const float* bias = (const float*)d_in[3];
    const int* index = (const int*)d_in[4];
    const float* weight_p = (const float*)d_in[5];
    const float* weight_out = (const float*)d_in[6];
    const int* rev = (const int*)d_in[7];
    const float* gates = (const float*)d_in[8];
    const int* gidx = (const int*)d_in[9];
    const float* bias_p = (const float*)d_in[10];
    const float* bias_out = (const float*)d_in[11];
    float* out = (float*)d_out;

    char* w = (char*)d_ws;
    unsigned short* jag_bf = (unsigned short*)w; w += (size_t)T_TOK * DDIM * 2;       // 16MB
    unsigned short* W1t    = (unsigned short*)w; w += (size_t)NEXP * DDIM * HDIM * 2; // 16MB
    unsigned short* Wpt    = (unsigned short*)w; w += (size_t)NEXP * DDIM * HDIM * 2; // 16MB
    unsigned short* Wot    = (unsigned short*)w; w += (size_t)NEXP * HDIM * DDIM * 2; // 16MB
    unsigned short* g_ws   = (unsigned short*)w; w += (size_t)NROWS * HDIM * 2;       // 32MB (blob)
    unsigned short* h_ws   = (unsigned short*)w; w += (size_t)NROWS * HDIM * 2;       // 32MB
    unsigned short* y_ws   = g_ws;   // blob dead after up-GEMM; reuse for y

    // prep: bf16 cast + weight transposes (B^T layout)
    cvt_bf16_k<<<(T_TOK * DDIM / 4 + 255) / 256, 256, 0, stream>>>(jagged, jag_bf, T_TOK * DDIM / 4);
    transpose_cast_k<<<dim3(HDIM / 32, DDIM / 32, NEXP), 256, 0, stream>>>(weight, W1t, DDIM, HDIM);
    transpose_cast_k<<<dim3(HDIM / 32, DDIM / 32, NEXP), 256, 0, stream>>>(weight_p, Wpt, DDIM, HDIM);
    transpose_cast_k<<<dim3(DDIM / 32, HDIM / 32, NEXP), 256, 0, stream>>>(weight_out, Wot, HDIM, DDIM);

    const int grid = (NROWS / BM2) * (HDIM / BN2);    // 64 * 4 = 256 blocks

    // g = gather(x) @ W + b   -> blob layout
    gemm256_sl_k<1><<<grid, 512, 0, stream>>>(jag_bf, index, DDIM, W1t, bias, nullptr, g_ws,
                                              offsets, HDIM, DDIM);
    // h = silu(g) * (gather(x) @ Wp + bp)
    gemm256_sl_k<2><<<grid, 512, 0, stream>>>(jag_bf, index, DDIM, Wpt, bias_p, g_ws, h_ws,
                                              offsets, HDIM, DDIM);
    // y = h @ Wout + bout
    gemm256_sl_k<0><<<grid, 512, 0, stream>>>(h_ws, nullptr, HDIM, Wot, bias_out, nullptr, y_ws,
                                              offsets, DDIM, HDIM);
    // out[t] = sum_k gates[gidx[t,k]] * y[rev[t,k]]
    combine_k<<<T_TOK, 256, 0, stream>>>(y_ws, rev, gates, gidx, out);
}

// Round 10
// 178.810 us; speedup vs baseline: 1.0097x; 1.0097x over previous
//
#include <hip/hip_runtime.h>
#include <hip/hip_bf16.h>

#define T_TOK 8192
#define DDIM 1024
#define HDIM 1024
#define NEXP 8
#define KTOP 2
#define NROWS (T_TOK * KTOP)

typedef __attribute__((ext_vector_type(8))) short bf16x8;
typedef __attribute__((ext_vector_type(4))) float f32x4;

__device__ __forceinline__ unsigned short f2bf(float f) {
    unsigned u = __builtin_bit_cast(unsigned, f);
    u += 0x7fffu + ((u >> 16) & 1u);   // RNE
    return (unsigned short)(u >> 16);
}
__device__ __forceinline__ float bf2f(unsigned short h) {
    return __builtin_bit_cast(float, (unsigned)h << 16);
}

// async global->LDS, 16B per lane; LDS dest wave-uniform base + lane*16.
__device__ __forceinline__ void gll16(const unsigned short* g, const unsigned short* l) {
    __builtin_amdgcn_global_load_lds(
        (const __attribute__((address_space(1))) unsigned int*)g,
        (__attribute__((address_space(3))) unsigned int*)l, 16, 0, 0);
}

// ---------------- prep kernels ----------------

__global__ __launch_bounds__(256) void cvt_bf16_k(const float* __restrict__ in,
                                                  unsigned short* __restrict__ out, int n4) {
    int i = blockIdx.x * 256 + threadIdx.x;
    if (i >= n4) return;
    float4 v = ((const float4*)in)[i];
    ushort4 o;
    o.x = f2bf(v.x); o.y = f2bf(v.y); o.z = f2bf(v.z); o.w = f2bf(v.w);
    ((ushort4*)out)[i] = o;
}

// in: [nmat][R][C] f32  ->  out: [nmat][C][R] bf16
__global__ __launch_bounds__(256) void transpose_cast_k(const float* __restrict__ in,
                                                        unsigned short* __restrict__ out,
                                                        int R, int C) {
    __shared__ unsigned short tile[32][33];
    int m = blockIdx.z;
    const float* src = in + (size_t)m * R * C;
    unsigned short* dst = out + (size_t)m * R * C;
    int c0 = blockIdx.x * 32, r0 = blockIdx.y * 32;
    int tx = threadIdx.x & 31, ty = threadIdx.x >> 5;
#pragma unroll
    for (int i = 0; i < 32; i += 8)
        tile[ty + i][tx] = f2bf(src[(size_t)(r0 + ty + i) * C + c0 + tx]);
    __syncthreads();
#pragma unroll
    for (int i = 0; i < 32; i += 8)
        dst[(size_t)(c0 + ty + i) * R + r0 + tx] = tile[tx][ty + i];
}

// --------- 256x256 GEMM, faithful m201 8-phase port (T1+T2+T3+T4+T5) ----------
// C = act(A @ Bt^T + bias). 512 thr = 8 waves (2Mx4N), per-wave 128x64 out.
// BK=64, 16 K-tiles, 2 dbuf x 4 half-tile regions (A by mi-half rows
// [0,64)u[128,192) / [64,128)u[192,256); B by ni-half cols (c&32)==0 / !=0).
// Per tile: 4 quadrant phases Q(qm,qn) = {ds-read (A 8 b128 on qn==0, reuse on
// qn==1; B 4 b128) ; stage ONE dead half-tile (2 gll16) ; barrier ; lgkm(0)+
// sched_barrier ; setprio(1) 16 MFMA setprio(0) ; barrier}. Stage placement by
// death schedule: Q0->A1(t+1), Q1->B1(t+1), Q2->A0(t+2), Q3->B0(t+2); each
// target region was lgkm-drained before the preceding barrier (WAR-safe).
// vmcnt(4) ONLY at tile boundaries (2 half-tiles stay in flight; RAW: boundary
// vmcnt+barrier publishes tile t+1's A1/B1 and earlier A0/B0).
// Swizzle: rows packed 2/128B line... here 1 row per 128B line; logical 16B
// chunk c stored at phys c^(row&7); gll writes linear; source pre-inverse-
// swizzled; reads XOR the same (rule 21c) -> ~0 conflicts (verified r5-r8).
// T1: XCD-chunked map (XCD x owns expert x's rows).
// VARIANT 0: out = acc+bias ; VARIANT 1: out = silu(Gin)*(acc+bias)

constexpr int BM2 = 256, BN2 = 256, BK2 = 64;
constexpr int NT2 = DDIM / BK2;   // 16 K-tiles
// LDS ushort map: A buf b at b*16384, half h at +h*8192; B at +32768 same.

template <int VARIANT>
__global__ __launch_bounds__(512) void gemm256_8q_k(
    const unsigned short* __restrict__ A, const int* __restrict__ rowidx, int lda,
    const unsigned short* __restrict__ Bt, const float* __restrict__ biasE,
    const unsigned short* __restrict__ Gin, unsigned short* __restrict__ Out,
    const int* __restrict__ offsets, int N, int K) {
    __shared__ __attribute__((aligned(16))) unsigned short lds[65536];  // 128 KiB

    // XCD-chunked map: 256 blocks, 8 XCDs, 32 each; brow-major within chunk.
    const int nbn = N / BN2;                          // 4
    int l = (blockIdx.x & 7) * 32 + (blockIdx.x >> 3);
    int brow = l / nbn, bcol = l % nbn;
    int row0 = brow * BM2, col0 = bcol * BN2;
    int e = 0;
    while (offsets[e + 1] <= row0) ++e;

    const unsigned short* Bte = Bt + (size_t)e * N * K;
    const float* bias = biasE + (size_t)e * N;

    int tid = threadIdx.x;
    int lane = tid & 63, wid = tid >> 6;
    int wm = wid >> 2, wn = wid & 3;                  // 2x4 wave grid
    int l15 = lane & 15, l4 = lane >> 4;

    // ---- staging source pointers (inverse swizzle; rule 21c) ----
    // gll dest is linear: instr q covers region bytes [wid*2048+q*1024,+1024),
    // lane at +lane*16 -> region-row ri = wid*16+q*8+(lane>>3), phys chunk
    // lane&7 -> logical chunk c = (lane&7)^(lane>>3).
    int srow = lane >> 3;
    int c8 = ((lane & 7) ^ srow) * 8;                 // bf16 elem offset of chunk
    const unsigned short* aS[2][2];
    const unsigned short* bS[2][2];
#pragma unroll
    for (int h = 0; h < 2; ++h)
#pragma unroll
        for (int q = 0; q < 2; ++q) {
            // A region h row ri -> global row (ri&63) + h*64 + (ri>>6)*128
            int r = (wid & 3) * 16 + q * 8 + srow + h * 64 + (wid >> 2) * 128;
            int ar = rowidx ? rowidx[row0 + r] : row0 + r;
            aS[h][q] = A + (size_t)ar * lda + c8;
            // B region h row ci -> global col (ci&31) + h*32 + (ci>>5)*64
            int cc = (wid & 1) * 16 + q * 8 + srow + h * 32 + (wid >> 1) * 64;
            bS[h][q] = Bte + (size_t)(col0 + cc) * K + c8;
        }
    unsigned wq = wid * 1024;                         // ushort offset of q=0 group

#define STG_A(BUF, H, T) { \
        gll16(aS[H][0] + (T) * BK2, lds + (BUF) * 16384 + (H) * 8192 + wq);       \
        gll16(aS[H][1] + (T) * BK2, lds + (BUF) * 16384 + (H) * 8192 + wq + 512); }
#define STG_B(BUF, H, T) { \
        gll16(bS[H][0] + (T) * BK2, lds + 32768 + (BUF) * 16384 + (H) * 8192 + wq);       \
        gll16(bS[H][1] + (T) * BK2, lds + 32768 + (BUF) * 16384 + (H) * 8192 + wq + 512); }

    // ---- read addressing (swizzled) ----
    const char* LB = (const char*)lds;
    int arow = (wm * 64 + l15) * 128;                 // byte, within A half
    int brw = (wn * 32 + l15) * 128;                  // byte, within B half
    int cx = l15 & 7;
    int ch0 = (l4 ^ cx) * 16;
    int ch1 = ((4 + l4) ^ cx) * 16;

    f32x4 acc[8][4] = {};
    bf16x8 fa[8], fb[4];

    // PHASE(BUF, QM, QN, LOADA, STG): one quadrant x K=64 (16 MFMA)
#define PHASE(BUF, QM, QN, LOADA, STG)                                        \
    {                                                                         \
        if (LOADA) {                                                          \
            const char* Ab_ = LB + (BUF) * 32768 + (QM) * 16384 + arow;       \
            _Pragma("unroll") for (int mi = 0; mi < 4; ++mi) {                \
                fa[mi]     = *(const bf16x8*)(Ab_ + mi * 2048 + ch0);         \
                fa[4 + mi] = *(const bf16x8*)(Ab_ + mi * 2048 + ch1);         \
            }                                                                 \
        }                                                                     \
        {                                                                     \
            const char* Bb_ = LB + 65536 + (BUF) * 32768 + (QN) * 16384 + brw;\
            fb[0] = *(const bf16x8*)(Bb_ + ch0);                              \
            fb[1] = *(const bf16x8*)(Bb_ + 2048 + ch0);                       \
            fb[2] = *(const bf16x8*)(Bb_ + ch1);                              \
            fb[3] = *(const bf16x8*)(Bb_ + 2048 + ch1);                       \
        }                                                                     \
        STG;                                                                  \
        __builtin_amdgcn_s_barrier();                                         \
        asm volatile("s_waitcnt lgkmcnt(0)" ::: "memory");                    \
        __builtin_amdgcn_sched_barrier(0);                                    \
        __builtin_amdgcn_s_setprio(1);                                        \
        _Pragma("unroll") for (int s = 0; s < 2; ++s)                         \
        _Pragma("unroll") for (int mi = 0; mi < 4; ++mi)                      \
        _Pragma("unroll") for (int n = 0; n < 2; ++n)                         \
            acc[(QM) * 4 + mi][(QN) * 2 + n] =                                \
                __builtin_amdgcn_mfma_f32_16x16x32_bf16(                      \
                    fa[s * 4 + mi], fb[s * 2 + n],                            \
                    acc[(QM) * 4 + mi][(QN) * 2 + n], 0, 0, 0);               \
        __builtin_amdgcn_s_setprio(0);                                        \
    }

#define TILE(BUF, OBUF, KT)                                                   \
    PHASE(BUF, 0, 0, true,  if ((KT) + 1 < NT2) STG_A(OBUF, 1, (KT) + 1))     \
    __builtin_amdgcn_s_barrier();                                             \
    PHASE(BUF, 0, 1, false, if ((KT) + 1 < NT2) STG_B(OBUF, 1, (KT) + 1))     \
    __builtin_amdgcn_s_barrier();                                             \
    PHASE(BUF, 1, 0, true,  if ((KT) + 2 < NT2) STG_A(BUF, 0, (KT) + 2))      \
    __builtin_amdgcn_s_barrier();                                             \
    PHASE(BUF, 1, 1, false, if ((KT) + 2 < NT2) STG_B(BUF, 0, (KT) + 2))      \
    if ((KT) <= NT2 - 3) {                                                    \
        asm volatile("s_waitcnt vmcnt(4)" ::: "memory");                      \
        __builtin_amdgcn_s_barrier();                                         \
    } else if ((KT) == NT2 - 2) {                                             \
        asm volatile("s_waitcnt vmcnt(0)" ::: "memory");                      \
        __builtin_amdgcn_s_barrier();                                         \
    }

    // prologue: tile 0 complete + A0/B0 of tile 1; vmcnt(4) leaves those 4
    STG_A(0, 0, 0) STG_B(0, 0, 0) STG_A(0, 1, 0) STG_B(0, 1, 0)
    STG_A(1, 0, 1) STG_B(1, 0, 1)
    asm volatile("s_waitcnt vmcnt(4)" ::: "memory");
    __builtin_amdgcn_s_barrier();

#pragma unroll 1
    for (int t = 0; t < NT2; t += 2) {
        TILE(0, 1, t)
        TILE(1, 0, t + 1)
    }
#undef TILE
#undef PHASE
#undef STG_A
#undef STG_B

    float bv[4];
#pragma unroll
    for (int ni = 0; ni < 4; ++ni)
        bv[ni] = bias[col0 + wn * 64 + ni * 16 + l15];

#pragma unroll
    for (int mi = 0; mi < 8; ++mi) {
        int orow_b = row0 + wm * 128 + mi * 16 + l4 * 4;
#pragma unroll
        for (int ni = 0; ni < 4; ++ni) {
            int ocol = col0 + wn * 64 + ni * 16 + l15;
#pragma unroll
            for (int q = 0; q < 4; ++q) {
                size_t oidx = (size_t)(orow_b + q) * N + ocol;
                float v = acc[mi][ni][q] + bv[ni];
                if (VARIANT == 1) {
                    float g = bf2f(Gin[oidx]);
                    float s = g / (1.0f + __expf(-g));
                    v = s * v;
                }
                Out[oidx] = f2bf(v);
            }
        }
    }
}

// ---------------- combine ----------------

__global__ __launch_bounds__(256) void combine_k(
    const unsigned short* __restrict__ Y, const int* __restrict__ rev,
    const float* __restrict__ gates, const int* __restrict__ gidx,
    float* __restrict__ out) {
    int t = blockIdx.x;
    int r0 = rev[2 * t], r1 = rev[2 * t + 1];
    float g0 = gates[gidx[2 * t]], g1 = gates[gidx[2 * t + 1]];
    const unsigned short* y0 = Y + (size_t)r0 * DDIM;
    const unsigned short* y1 = Y + (size_t)r1 * DDIM;
    int d = threadIdx.x * 4;
    ushort4 a = *(const ushort4*)(y0 + d);
    ushort4 b = *(const ushort4*)(y1 + d);
    float4 r;
    r.x = g0 * bf2f(a.x) + g1 * bf2f(b.x);
    r.y = g0 * bf2f(a.y) + g1 * bf2f(b.y);
    r.z = g0 * bf2f(a.z) + g1 * bf2f(b.z);
    r.w = g0 * bf2f(a.w) + g1 * bf2f(b.w);
    *(float4*)(out + (size_t)t * DDIM + d) = r;
}

// ---------------- launch ----------------

extern "C" void kernel_launch(void* const* d_in, const int* in_sizes, int n_in,
                              void* d_out, int out_size, void* d_ws, size_t ws_size,
                              hipStream_t stream) {
    const int* offsets = (const int*)d_in[0];
    const float* jagged = (const float*)d_in[1];
    const float* weight = (const float*)d_in[2];
    const float* bias = (const float*)d_in[3];
    const int* index = (const int*)d_in[4];
    const float* weight_p = (const float*)d_in[5];
    const float* weight_out = (const float*)d_in[6];
    const int* rev = (const int*)d_in[7];
    const float* gates = (const float*)d_in[8];
    const int* gidx = (const int*)d_in[9];
    const float* bias_p = (const float*)d_in[10];
    const float* bias_out = (const float*)d_in[11];
    float* out = (float*)d_out;

    char* w = (char*)d_ws;
    unsigned short* jag_bf = (unsigned short*)w; w += (size_t)T_TOK * DDIM * 2;       // 16MB
    unsigned short* W1t    = (unsigned short*)w; w += (size_t)NEXP * DDIM * HDIM * 2; // 16MB
    unsigned short* Wpt    = (unsigned short*)w; w += (size_t)NEXP * DDIM * HDIM * 2; // 16MB
    unsigned short* Wot    = (unsigned short*)w; w += (size_t)NEXP * HDIM * DDIM * 2; // 16MB
    unsigned short* g_ws   = (unsigned short*)w; w += (size_t)NROWS * HDIM * 2;       // 32MB
    unsigned short* h_ws   = (unsigned short*)w; w += (size_t)NROWS * HDIM * 2;       // 32MB
    unsigned short* y_ws   = g_ws;   // g dead after u-GEMM epilogue; reuse for y

    // prep: bf16 cast + weight transposes (B^T layout)
    cvt_bf16_k<<<(T_TOK * DDIM / 4 + 255) / 256, 256, 0, stream>>>(jagged, jag_bf, T_TOK * DDIM / 4);
    transpose_cast_k<<<dim3(HDIM / 32, DDIM / 32, NEXP), 256, 0, stream>>>(weight, W1t, DDIM, HDIM);
    transpose_cast_k<<<dim3(HDIM / 32, DDIM / 32, NEXP), 256, 0, stream>>>(weight_p, Wpt, DDIM, HDIM);
    transpose_cast_k<<<dim3(DDIM / 32, HDIM / 32, NEXP), 256, 0, stream>>>(weight_out, Wot, HDIM, DDIM);

    const int grid = (NROWS / BM2) * (HDIM / BN2);    // 64 * 4 = 256 blocks

    // g = gather(x) @ W + b
    gemm256_8q_k<0><<<grid, 512, 0, stream>>>(jag_bf, index, DDIM, W1t, bias, nullptr, g_ws,
                                              offsets, HDIM, DDIM);
    // h = silu(g) * (gather(x) @ Wp + bp)
    gemm256_8q_k<1><<<grid, 512, 0, stream>>>(jag_bf, index, DDIM, Wpt, bias_p, g_ws, h_ws,
                                              offsets, HDIM, DDIM);
    // y = h @ Wout + bout
    gemm256_8q_k<0><<<grid, 512, 0, stream>>>(h_ws, nullptr, HDIM, Wot, bias_out, nullptr, y_ws,
                                              offsets, DDIM, HDIM);
    // out[t] = sum_k gates[gidx[t,k]] * y[rev[t,k]]
    combine_k<<<T_TOK, 256, 0, stream>>>(y_ws, rev, gates, gidx, out);
}

// Round 11
// 175.767 us; speedup vs baseline: 1.0272x; 1.0173x over previous
//
#include <hip/hip_runtime.h>
#include <hip/hip_bf16.h>

#define T_TOK 8192
#define DDIM 1024
#define HDIM 1024
#define NEXP 8
#define KTOP 2
#define NROWS (T_TOK * KTOP)

typedef __attribute__((ext_vector_type(8))) short bf16x8;
typedef __attribute__((ext_vector_type(4))) float f32x4;

__device__ __forceinline__ unsigned short f2bf(float f) {
    unsigned u = __builtin_bit_cast(unsigned, f);
    u += 0x7fffu + ((u >> 16) & 1u);   // RNE
    return (unsigned short)(u >> 16);
}
__device__ __forceinline__ float bf2f(unsigned short h) {
    return __builtin_bit_cast(float, (unsigned)h << 16);
}

// async global->LDS, 16B per lane; LDS dest wave-uniform base + lane*16.
__device__ __forceinline__ void gll16(const unsigned short* g, const unsigned short* l) {
    __builtin_amdgcn_global_load_lds(
        (const __attribute__((address_space(1))) unsigned int*)g,
        (__attribute__((address_space(3))) unsigned int*)l, 16, 0, 0);
}

// ---------------- prep kernels ----------------

__global__ __launch_bounds__(256) void cvt_bf16_k(const float* __restrict__ in,
                                                  unsigned short* __restrict__ out, int n4) {
    int i = blockIdx.x * 256 + threadIdx.x;
    if (i >= n4) return;
    float4 v = ((const float4*)in)[i];
    ushort4 o;
    o.x = f2bf(v.x); o.y = f2bf(v.y); o.z = f2bf(v.z); o.w = f2bf(v.w);
    ((ushort4*)out)[i] = o;
}

// in: [nmat][R][C] f32  ->  out: [nmat][C][R] bf16
__global__ __launch_bounds__(256) void transpose_cast_k(const float* __restrict__ in,
                                                        unsigned short* __restrict__ out,
                                                        int R, int C) {
    __shared__ unsigned short tile[32][33];
    int m = blockIdx.z;
    const float* src = in + (size_t)m * R * C;
    unsigned short* dst = out + (size_t)m * R * C;
    int c0 = blockIdx.x * 32, r0 = blockIdx.y * 32;
    int tx = threadIdx.x & 31, ty = threadIdx.x >> 5;
#pragma unroll
    for (int i = 0; i < 32; i += 8)
        tile[ty + i][tx] = f2bf(src[(size_t)(r0 + ty + i) * C + c0 + tx]);
    __syncthreads();
#pragma unroll
    for (int i = 0; i < 32; i += 8)
        dst[(size_t)(c0 + ty + i) * R + r0 + tx] = tile[tx][ty + i];
}

// --------- 256x256 GEMM, (qm,k-slice) phasing: B read ONCE per tile ----------
// C = act(A @ Bt^T + bias). 512 thr = 8 waves (2Mx4N), per-wave 128x64 out.
// BK=64, 16 K-tiles, 2 dbuf. Phases per tile: P(qm,s) = {ds-read fa (4 b128;
// + fb s-slice 4 b128 on qm==0) ; stage dead region ; lgkm(0)+sched_barrier ;
// setprio(1) 16 MFMA setprio(0) ; barrier}. fb0/fb1 (8 frags) live across the
// tile -> B LDS reads halve vs qn-phasing (24 vs 32 b128/wave/tile); bursts
// 8,8,4,4. ONE barrier/phase: death of region read at phase X is per-wave at
// X's lgkm(0) (pre-MFMA), global at X's post-MFMA barrier -> stage at X+1 ok.
// Stage schedule: P00->A1(t+1); P10->A0(t+2)+B0(t+2); P11->B1(t+2).
//   WAR: A1(t-1) dead end-P11(t-1) ok; A0(t)/B0(t)/B1(t) dead end-P01(t) ok.
//   RAW: boundary vmcnt(6) allows {A0,B0,B1}(t+2) in flight, waits A1(t+1)
//   (staged 3 phases prior) and older -> barrier publishes tile t+1.
// Swizzle: 16B chunk c of row r stored at phys c^(r&7); gll writes linear from
// inverse-swizzled global src; reads XOR the same (rule 21c) -> 0 conflicts.
// T1: XCD-chunked map (XCD x owns expert x's rows).
// VARIANT 0: out = acc+bias ; VARIANT 1: out = silu(Gin)*(acc+bias)

constexpr int BM2 = 256, BN2 = 256, BK2 = 64;
constexpr int NT2 = DDIM / BK2;   // 16 K-tiles
// LDS ushort map: A buf b at b*16384, half h at +h*8192; B at +32768 same.

template <int VARIANT>
__global__ __launch_bounds__(512) void gemm256_ks_k(
    const unsigned short* __restrict__ A, const int* __restrict__ rowidx, int lda,
    const unsigned short* __restrict__ Bt, const float* __restrict__ biasE,
    const unsigned short* __restrict__ Gin, unsigned short* __restrict__ Out,
    const int* __restrict__ offsets, int N, int K) {
    __shared__ __attribute__((aligned(16))) unsigned short lds[65536];  // 128 KiB

    // XCD-chunked map: 256 blocks, 8 XCDs, 32 each; brow-major within chunk.
    const int nbn = N / BN2;                          // 4
    int l = (blockIdx.x & 7) * 32 + (blockIdx.x >> 3);
    int brow = l / nbn, bcol = l % nbn;
    int row0 = brow * BM2, col0 = bcol * BN2;
    int e = 0;
    while (offsets[e + 1] <= row0) ++e;

    const unsigned short* Bte = Bt + (size_t)e * N * K;
    const float* bias = biasE + (size_t)e * N;

    int tid = threadIdx.x;
    int lane = tid & 63, wid = tid >> 6;
    int wm = wid >> 2, wn = wid & 3;                  // 2x4 wave grid
    int l15 = lane & 15, l4 = lane >> 4;

    // ---- staging source pointers (inverse swizzle; rule 21c) ----
    int srow = lane >> 3;
    int c8 = ((lane & 7) ^ srow) * 8;                 // bf16 elem offset of chunk
    const unsigned short* aS[2][2];
    const unsigned short* bS[2][2];
#pragma unroll
    for (int h = 0; h < 2; ++h)
#pragma unroll
        for (int q = 0; q < 2; ++q) {
            int r = (wid & 3) * 16 + q * 8 + srow + h * 64 + (wid >> 2) * 128;
            int ar = rowidx ? rowidx[row0 + r] : row0 + r;
            aS[h][q] = A + (size_t)ar * lda + c8;
            int cc = (wid & 1) * 16 + q * 8 + srow + h * 32 + (wid >> 1) * 64;
            bS[h][q] = Bte + (size_t)(col0 + cc) * K + c8;
        }
    unsigned wq = wid * 1024;                         // ushort offset of q=0 group

#define STG_A(BUF, H, T) { \
        gll16(aS[H][0] + (T) * BK2, lds + (BUF) * 16384 + (H) * 8192 + wq);       \
        gll16(aS[H][1] + (T) * BK2, lds + (BUF) * 16384 + (H) * 8192 + wq + 512); }
#define STG_B(BUF, H, T) { \
        gll16(bS[H][0] + (T) * BK2, lds + 32768 + (BUF) * 16384 + (H) * 8192 + wq);       \
        gll16(bS[H][1] + (T) * BK2, lds + 32768 + (BUF) * 16384 + (H) * 8192 + wq + 512); }

    // ---- read addressing (swizzled) ----
    const char* LB = (const char*)lds;
    int arow = (wm * 64 + l15) * 128;                 // byte, within A half
    int brw = (wn * 32 + l15) * 128;                  // byte, within B half
    int cx = l15 & 7;
    int ch0 = (l4 ^ cx) * 16;
    int ch1 = ((4 + l4) ^ cx) * 16;

    f32x4 acc[8][4] = {};
    bf16x8 fa[4], fb0[4], fb1[4];

#define RD_FA(BUF, QM, CH) {                                                  \
        const char* Ab_ = LB + (BUF) * 32768 + (QM) * 16384 + arow;           \
        fa[0] = *(const bf16x8*)(Ab_ + 0 * 2048 + (CH));                      \
        fa[1] = *(const bf16x8*)(Ab_ + 1 * 2048 + (CH));                      \
        fa[2] = *(const bf16x8*)(Ab_ + 2 * 2048 + (CH));                      \
        fa[3] = *(const bf16x8*)(Ab_ + 3 * 2048 + (CH)); }
#define RD_FB(BUF, FB, CH) {                                                  \
        const char* Bb_ = LB + 65536 + (BUF) * 32768 + brw;                   \
        FB[0] = *(const bf16x8*)(Bb_ + (CH));                                 \
        FB[1] = *(const bf16x8*)(Bb_ + 2048 + (CH));                          \
        FB[2] = *(const bf16x8*)(Bb_ + 16384 + (CH));                         \
        FB[3] = *(const bf16x8*)(Bb_ + 16384 + 2048 + (CH)); }
#define MFMA16(QM, FB)                                                        \
    asm volatile("s_waitcnt lgkmcnt(0)" ::: "memory");                        \
    __builtin_amdgcn_sched_barrier(0);                                        \
    __builtin_amdgcn_s_setprio(1);                                            \
    _Pragma("unroll") for (int mi = 0; mi < 4; ++mi)                          \
    _Pragma("unroll") for (int ni = 0; ni < 4; ++ni)                          \
        acc[(QM) * 4 + mi][ni] = __builtin_amdgcn_mfma_f32_16x16x32_bf16(     \
            fa[mi], FB[ni], acc[(QM) * 4 + mi][ni], 0, 0, 0);                 \
    __builtin_amdgcn_s_setprio(0);

    // prologue: tile 0 complete (8) + A0(1),B(1) (6); vmcnt(6) keeps those 6
    STG_A(0, 0, 0) STG_A(0, 1, 0) STG_B(0, 0, 0) STG_B(0, 1, 0)
    STG_A(1, 0, 1) STG_B(1, 0, 1) STG_B(1, 1, 1)
    asm volatile("s_waitcnt vmcnt(6)" ::: "memory");
    __builtin_amdgcn_s_barrier();

#pragma unroll 1
    for (int t = 0; t < NT2; ++t) {
        int bc = t & 1, bo = bc ^ 1;
        // ---- P00: fa(qm0,s0) + fb s0; stage A1(t+1); MFMA qm0 x s0 ----
        RD_FA(bc, 0, ch0)
        RD_FB(bc, fb0, ch0)
        if (t + 1 < NT2) STG_A(bo, 1, t + 1)
        MFMA16(0, fb0)
        __builtin_amdgcn_s_barrier();
        // ---- P01: fa(qm0,s1) + fb s1; MFMA qm0 x s1 ----
        RD_FA(bc, 0, ch1)
        RD_FB(bc, fb1, ch1)
        MFMA16(0, fb1)
        __builtin_amdgcn_s_barrier();
        // ---- P10: fa(qm1,s0); stage A0(t+2)+B0(t+2); MFMA qm1 x s0 ----
        RD_FA(bc, 1, ch0)
        if (t + 2 < NT2) { STG_A(bc, 0, t + 2) STG_B(bc, 0, t + 2) }
        MFMA16(1, fb0)
        __builtin_amdgcn_s_barrier();
        // ---- P11: fa(qm1,s1); stage B1(t+2); MFMA qm1 x s1; boundary ----
        RD_FA(bc, 1, ch1)
        if (t + 2 < NT2) STG_B(bc, 1, t + 2)
        MFMA16(1, fb1)
        if (t + 1 < NT2) {
            if (t + 2 < NT2) { asm volatile("s_waitcnt vmcnt(6)" ::: "memory"); }
            else             { asm volatile("s_waitcnt vmcnt(0)" ::: "memory"); }
            __builtin_amdgcn_s_barrier();
        }
    }
#undef MFMA16
#undef RD_FB
#undef RD_FA
#undef STG_B
#undef STG_A

    float bv[4];
#pragma unroll
    for (int ni = 0; ni < 4; ++ni)
        bv[ni] = bias[col0 + wn * 64 + ni * 16 + l15];

#pragma unroll
    for (int mi = 0; mi < 8; ++mi) {
        int orow_b = row0 + wm * 128 + mi * 16 + l4 * 4;
#pragma unroll
        for (int ni = 0; ni < 4; ++ni) {
            int ocol = col0 + wn * 64 + ni * 16 + l15;
#pragma unroll
            for (int q = 0; q < 4; ++q) {
                size_t oidx = (size_t)(orow_b + q) * N + ocol;
                float v = acc[mi][ni][q] + bv[ni];
                if (VARIANT == 1) {
                    float g = bf2f(Gin[oidx]);
                    float s = g / (1.0f + __expf(-g));
                    v = s * v;
                }
                Out[oidx] = f2bf(v);
            }
        }
    }
}

// ---------------- combine ----------------

__global__ __launch_bounds__(256) void combine_k(
    const unsigned short* __restrict__ Y, const int* __restrict__ rev,
    const float* __restrict__ gates, const int* __restrict__ gidx,
    float* __restrict__ out) {
    int t = blockIdx.x;
    int r0 = rev[2 * t], r1 = rev[2 * t + 1];
    float g0 = gates[gidx[2 * t]], g1 = gates[gidx[2 * t + 1]];
    const unsigned short* y0 = Y + (size_t)r0 * DDIM;
    const unsigned short* y1 = Y + (size_t)r1 * DDIM;
    int d = threadIdx.x * 4;
    ushort4 a = *(const ushort4*)(y0 + d);
    ushort4 b = *(const ushort4*)(y1 + d);
    float4 r;
    r.x = g0 * bf2f(a.x) + g1 * bf2f(b.x);
    r.y = g0 * bf2f(a.y) + g1 * bf2f(b.y);
    r.z = g0 * bf2f(a.z) + g1 * bf2f(b.z);
    r.w = g0 * bf2f(a.w) + g1 * bf2f(b.w);
    *(float4*)(out + (size_t)t * DDIM + d) = r;
}

// ---------------- launch ----------------

extern "C" void kernel_launch(void* const* d_in, const int* in_sizes, int n_in,
                              void* d_out, int out_size, void* d_ws, size_t ws_size,
                              hipStream_t stream) {
    const int* offsets = (const int*)d_in[0];
    const float* jagged = (const float*)d_in[1];
    const float* weight = (const float*)d_in[2];
    const float* bias = (const float*)d_in[3];
    const int* index = (const int*)d_in[4];
    const float* weight_p = (const float*)d_in[5];
    const float* weight_out = (const float*)d_in[6];
    const int* rev = (const int*)d_in[7];
    const float* gates = (const float*)d_in[8];
    const int* gidx = (const int*)d_in[9];
    const float* bias_p = (const float*)d_in[10];
    const float* bias_out = (const float*)d_in[11];
    float* out = (float*)d_out;

    char* w = (char*)d_ws;
    unsigned short* jag_bf = (unsigned short*)w; w += (size_t)T_TOK * DDIM * 2;       // 16MB
    unsigned short* W1t    = (unsigned short*)w; w += (size_t)NEXP * DDIM * HDIM * 2; // 16MB
    unsigned short* Wpt    = (unsigned short*)w; w += (size_t)NEXP * DDIM * HDIM * 2; // 16MB
    unsigned short* Wot    = (unsigned short*)w; w += (size_t)NEXP * HDIM * DDIM * 2; // 16MB
    unsigned short* g_ws   = (unsigned short*)w; w += (size_t)NROWS * HDIM * 2;       // 32MB
    unsigned short* h_ws   = (unsigned short*)w; w += (size_t)NROWS * HDIM * 2;       // 32MB
    unsigned short* y_ws   = g_ws;   // g dead after u-GEMM epilogue; reuse for y

    // prep: bf16 cast + weight transposes (B^T layout)
    cvt_bf16_k<<<(T_TOK * DDIM / 4 + 255) / 256, 256, 0, stream>>>(jagged, jag_bf, T_TOK * DDIM / 4);
    transpose_cast_k<<<dim3(HDIM / 32, DDIM / 32, NEXP), 256, 0, stream>>>(weight, W1t, DDIM, HDIM);
    transpose_cast_k<<<dim3(HDIM / 32, DDIM / 32, NEXP), 256, 0, stream>>>(weight_p, Wpt, DDIM, HDIM);
    transpose_cast_k<<<dim3(DDIM / 32, HDIM / 32, NEXP), 256, 0, stream>>>(weight_out, Wot, HDIM, DDIM);

    const int grid = (NROWS / BM2) * (HDIM / BN2);    // 64 * 4 = 256 blocks

    // g = gather(x) @ W + b
    gemm256_ks_k<0><<<grid, 512, 0, stream>>>(jag_bf, index, DDIM, W1t, bias, nullptr, g_ws,
                                              offsets, HDIM, DDIM);
    // h = silu(g) * (gather(x) @ Wp + bp)
    gemm256_ks_k<1><<<grid, 512, 0, stream>>>(jag_bf, index, DDIM, Wpt, bias_p, g_ws, h_ws,
                                              offsets, HDIM, DDIM);
    // y = h @ Wout + bout
    gemm256_ks_k<0><<<grid, 512, 0, stream>>>(h_ws, nullptr, HDIM, Wot, bias_out, nullptr, y_ws,
                                              offsets, DDIM, HDIM);
    // out[t] = sum_k gates[gidx[t,k]] * y[rev[t,k]]
    combine_k<<<T_TOK, 256, 0, stream>>>(y_ws, rev, gates, gidx, out);
}